// Round 4
// baseline (405.619 us; speedup 1.0000x reference)
//
#include <hip/hip_runtime.h>
#include <hip/hip_bf16.h>

// RPL_Asymm_3d_spconv: 3x (3-tap gathered GEMM -> BN(train) -> sigmoid), then (s1+s2+s3)*features
// N=131072, C=256. bf16 MFMA path.
//
// Round 4 = Round 3 with the nontemporal-store type fix (ext-vector f32x4, not HIP float4):
//  - 256x256xBK64 8-wave phase-split GEMM (T3+T4+T5 stack)
//  - taps flattened into K (12 K-tiles of 64), A gathered via VGPR-held indices
//  - LDS double-buffer, XOR chunk swizzle p = g ^ (row&7) (source-side + read-side)
//  - 4 phases/K-tile: {ds_read subtile | stage t+1} barrier setprio MFMA barrier
//  - single counted drain point per K-tile (vmcnt(0) at boundary), raw s_barrier only
//  - BN stats fused in epilogue; one final apply pass reading bf16 features

#define NP 131072
#define CC 256
#define BM 256
#define BK 64
#define ATILE (BM * BK)   // 16384 elems (32 KiB)
#define BTILE (256 * BK)

typedef __attribute__((ext_vector_type(4))) float f32x4;
typedef __attribute__((ext_vector_type(8))) short bf16x8;

__device__ __forceinline__ unsigned short f2bf(float f) {
    unsigned int u = __float_as_uint(f);
    u += 0x7FFFu + ((u >> 16) & 1u);   // RNE
    return (unsigned short)(u >> 16);
}
__device__ __forceinline__ float bf2f(unsigned short s) {
    return __uint_as_float(((unsigned int)s) << 16);
}

__device__ __forceinline__ void gload_lds16(const void* g, void* l) {
    __builtin_amdgcn_global_load_lds(
        (const __attribute__((address_space(1))) unsigned int*)g,
        (__attribute__((address_space(3))) unsigned int*)l, 16, 0, 0);
}

__global__ void zero_stats_k(float* stats) {
    int i = blockIdx.x * 256 + threadIdx.x;
    if (i < 3 * 2 * CC) stats[i] = 0.f;
}

__global__ void cast_features_k(const float* __restrict__ f, unsigned short* __restrict__ fb) {
    size_t e = ((size_t)blockIdx.x * 256 + threadIdx.x) * 8;
    const size_t tot = (size_t)(NP + 1) * CC;
    if (e >= tot) return;
    unsigned short tmp[8];
    if (e >= (size_t)NP * CC) {
        #pragma unroll
        for (int j = 0; j < 8; ++j) tmp[j] = 0;  // pad row
    } else {
        float4 v0 = *(const float4*)(f + e);
        float4 v1 = *(const float4*)(f + e + 4);
        tmp[0] = f2bf(v0.x); tmp[1] = f2bf(v0.y); tmp[2] = f2bf(v0.z); tmp[3] = f2bf(v0.w);
        tmp[4] = f2bf(v1.x); tmp[5] = f2bf(v1.y); tmp[6] = f2bf(v1.z); tmp[7] = f2bf(v1.w);
    }
    *(bf16x8*)(fb + e) = *(bf16x8*)tmp;
}

// wbT[m][cout][cin] = W_m[tap][cin][cout], m = axis*3+tap
__global__ void cast_weights_k(const float* __restrict__ W1, const float* __restrict__ W2,
                               const float* __restrict__ W3, unsigned short* __restrict__ wbT) {
    int bid  = blockIdx.x;        // 0..2303
    int m    = bid >> 8;          // 0..8
    int cout = bid & 255;
    int cin  = threadIdx.x;
    const float* W = (m < 3) ? W1 : (m < 6) ? W2 : W3;
    int tap = m - (m / 3) * 3;
    float v = W[((size_t)tap * CC + cin) * CC + cout];
    wbT[((size_t)m * CC + cout) * CC + cin] = f2bf(v);
}

#define MFMA16(a, b, c) __builtin_amdgcn_mfma_f32_16x16x32_bf16((a), (b), (c), 0, 0, 0)
#define LDF(base, row, swz) (*(const bf16x8*)((base) + (row) * BK + (swz)))

__global__ __launch_bounds__(512, 2)
void gemm_conv_fused_k(const unsigned short* __restrict__ fb,
                       const unsigned short* __restrict__ wbT,
                       const int* __restrict__ nbr1, const int* __restrict__ nbr2,
                       const int* __restrict__ nbr3,
                       unsigned short* __restrict__ hbase,
                       float* __restrict__ statsBase) {
    __shared__ unsigned short As[2 * ATILE];   // 64 KiB
    __shared__ unsigned short Bs[2 * BTILE];   // 64 KiB
    __shared__ float colsum[256];
    __shared__ float colsq[256];

    const int axis = blockIdx.y;
    const int* nbr = (axis == 0) ? nbr1 : (axis == 1) ? nbr2 : nbr3;
    const unsigned short* wA = wbT + (size_t)axis * 3 * CC * CC;
    unsigned short* h = hbase + (size_t)axis * NP * CC;
    float* stats = statsBase + axis * 2 * CC;

    const int tid     = threadIdx.x;
    const int lane    = tid & 63;
    const int wave    = tid >> 6;
    const int rowBase = blockIdx.x * BM;

    if (tid < 256) { colsum[tid] = 0.f; colsq[tid] = 0.f; }

    // per-thread staging constants: 4 loads each for A and B per K-tile
    int rstage[4], srcOff[4];
    int gA0[4], gA1[4], gA2[4];
    #pragma unroll
    for (int u = 0; u < 4; ++u) {
        int idx = u * 512 + tid;          // 16B-granule index within 256x64 tile
        int r = idx >> 3, p = idx & 7;
        rstage[u] = r;
        srcOff[u] = (p ^ (r & 7)) * 8;    // source element offset (inverse swizzle)
        int gi = rowBase + r;
        gA0[u] = nbr[(size_t)gi * 3 + 0];
        gA1[u] = nbr[(size_t)gi * 3 + 1];
        gA2[u] = nbr[(size_t)gi * 3 + 2];
    }

#define STAGE_A(u, Abuf, tapsel, kkE) do {                                    \
        int gr_ = ((tapsel) == 0) ? gA0[u] : ((tapsel) == 1) ? gA1[u] : gA2[u]; \
        gload_lds16(fb + (size_t)gr_ * CC + (kkE) + srcOff[u],                \
                    (Abuf) + ((u) * 512 + wave * 64) * 8);                    \
    } while (0)
#define STAGE_B(u, Bbuf, wTt, kkE)                                            \
        gload_lds16((wTt) + (size_t)rstage[u] * CC + (kkE) + srcOff[u],       \
                    (Bbuf) + ((u) * 512 + wave * 64) * 8)

    const int wr = wave >> 2;             // 0..1
    const int wc = wave & 3;              // 0..3
    const int fr = lane & 15;
    const int kq = lane >> 4;
    const int swz0 = (kq ^ (fr & 7)) * 8;        // ks=0 chunk (logical 0..3)
    const int swz1 = ((4 + kq) ^ (fr & 7)) * 8;  // ks=1 chunk (logical 4..7)
    const int rA = wr * 128 + fr;
    const int rB = wc * 64 + fr;

    f32x4 acc[8][4] = {};

    // prologue: stage K-tile 0 (tap 0, kk 0) then full drain
    STAGE_A(0, As, 0, 0); STAGE_A(1, As, 0, 0); STAGE_A(2, As, 0, 0); STAGE_A(3, As, 0, 0);
    STAGE_B(0, Bs, wA, 0); STAGE_B(1, Bs, wA, 0); STAGE_B(2, Bs, wA, 0); STAGE_B(3, Bs, wA, 0);
    __syncthreads();   // vmcnt(0)+lgkmcnt(0)+barrier once; also covers colsum init

    for (int t = 0; t < 12; ++t) {
        unsigned short* Ac = As + (t & 1) * ATILE;
        unsigned short* Bc = Bs + (t & 1) * BTILE;
        unsigned short* An = As + ((t & 1) ^ 1) * ATILE;
        unsigned short* Bn = Bs + ((t & 1) ^ 1) * BTILE;
        const int t1 = t + 1;
        const int tap1 = t1 >> 2;
        const int kk1 = (t1 & 3) * BK;
        const unsigned short* wT1 = wA + (size_t)tap1 * CC * CC;
        const bool st = (t < 11);

        bf16x8 aF[4][2], bLo[2][2], bHi[2][2];

        // ---------- phase 0: aF(m0..3) + bLo(n0..1); stage A0,A1,B0(t+1)
        #pragma unroll
        for (int m = 0; m < 4; ++m) {
            aF[m][0] = LDF(Ac, rA + m * 16, swz0);
            aF[m][1] = LDF(Ac, rA + m * 16, swz1);
        }
        #pragma unroll
        for (int n = 0; n < 2; ++n) {
            bLo[n][0] = LDF(Bc, rB + n * 16, swz0);
            bLo[n][1] = LDF(Bc, rB + n * 16, swz1);
        }
        if (st) { STAGE_A(0, An, tap1, kk1); STAGE_A(1, An, tap1, kk1); STAGE_B(0, Bn, wT1, kk1); }
        __builtin_amdgcn_s_barrier();
        __builtin_amdgcn_s_setprio(1);
        #pragma unroll
        for (int m = 0; m < 4; ++m)
            #pragma unroll
            for (int n = 0; n < 2; ++n) {
                acc[m][n] = MFMA16(aF[m][0], bLo[n][0], acc[m][n]);
                acc[m][n] = MFMA16(aF[m][1], bLo[n][1], acc[m][n]);
            }
        __builtin_amdgcn_s_setprio(0);
        __builtin_amdgcn_s_barrier();

        // ---------- phase 1: bHi(n2..3); stage A2,A3,B1(t+1)
        #pragma unroll
        for (int n = 0; n < 2; ++n) {
            bHi[n][0] = LDF(Bc, rB + (n + 2) * 16, swz0);
            bHi[n][1] = LDF(Bc, rB + (n + 2) * 16, swz1);
        }
        if (st) { STAGE_A(2, An, tap1, kk1); STAGE_A(3, An, tap1, kk1); STAGE_B(1, Bn, wT1, kk1); }
        __builtin_amdgcn_s_barrier();
        __builtin_amdgcn_s_setprio(1);
        #pragma unroll
        for (int m = 0; m < 4; ++m)
            #pragma unroll
            for (int n = 0; n < 2; ++n) {
                acc[m][n + 2] = MFMA16(aF[m][0], bHi[n][0], acc[m][n + 2]);
                acc[m][n + 2] = MFMA16(aF[m][1], bHi[n][1], acc[m][n + 2]);
            }
        __builtin_amdgcn_s_setprio(0);
        __builtin_amdgcn_s_barrier();

        // ---------- phase 2: aF(m4..7) overwrite; stage B2,B3(t+1)
        #pragma unroll
        for (int m = 0; m < 4; ++m) {
            aF[m][0] = LDF(Ac, rA + (m + 4) * 16, swz0);
            aF[m][1] = LDF(Ac, rA + (m + 4) * 16, swz1);
        }
        if (st) { STAGE_B(2, Bn, wT1, kk1); STAGE_B(3, Bn, wT1, kk1); }
        __builtin_amdgcn_s_barrier();
        __builtin_amdgcn_s_setprio(1);
        #pragma unroll
        for (int m = 0; m < 4; ++m)
            #pragma unroll
            for (int n = 0; n < 2; ++n) {
                acc[m + 4][n + 2] = MFMA16(aF[m][0], bHi[n][0], acc[m + 4][n + 2]);
                acc[m + 4][n + 2] = MFMA16(aF[m][1], bHi[n][1], acc[m + 4][n + 2]);
            }
        __builtin_amdgcn_s_setprio(0);
        __builtin_amdgcn_s_barrier();

        // ---------- phase 3: no reads/stages; MFMA (m4..7 x n0..1); boundary drain
        __builtin_amdgcn_s_setprio(1);
        #pragma unroll
        for (int m = 0; m < 4; ++m)
            #pragma unroll
            for (int n = 0; n < 2; ++n) {
                acc[m + 4][n] = MFMA16(aF[m][0], bLo[n][0], acc[m + 4][n]);
                acc[m + 4][n] = MFMA16(aF[m][1], bLo[n][1], acc[m + 4][n]);
            }
        __builtin_amdgcn_s_setprio(0);
        if (st) asm volatile("s_waitcnt vmcnt(0)" ::: "memory");
        __builtin_amdgcn_s_barrier();
    }

    // epilogue: C/D layout col=lane&15, row=(lane>>4)*4+reg; h store + fused stats
    const int orow = (lane >> 4) * 4;
    float psum[4], psq[4];
    #pragma unroll
    for (int n = 0; n < 4; ++n) { psum[n] = 0.f; psq[n] = 0.f; }
    #pragma unroll
    for (int m = 0; m < 8; ++m) {
        #pragma unroll
        for (int n = 0; n < 4; ++n) {
            int col = wc * 64 + n * 16 + fr;
            int row = rowBase + wr * 128 + m * 16 + orow;
            #pragma unroll
            for (int j = 0; j < 4; ++j) {
                unsigned short hb = f2bf(acc[m][n][j]);
                float v = bf2f(hb);
                __builtin_nontemporal_store(hb, &h[(size_t)(row + j) * CC + col]);
                psum[n] += v;
                psq[n]  += v * v;
            }
        }
    }
    #pragma unroll
    for (int n = 0; n < 4; ++n) {
        psum[n] += __shfl_xor(psum[n], 16);
        psum[n] += __shfl_xor(psum[n], 32);
        psq[n]  += __shfl_xor(psq[n], 16);
        psq[n]  += __shfl_xor(psq[n], 32);
    }
    if ((lane >> 4) == 0) {
        #pragma unroll
        for (int n = 0; n < 4; ++n) {
            int cl = wc * 64 + n * 16 + fr;
            atomicAdd(&colsum[cl], psum[n]);
            atomicAdd(&colsq[cl],  psq[n]);
        }
    }
    __syncthreads();
    if (tid < 256) {
        atomicAdd(&stats[tid],      colsum[tid]);
        atomicAdd(&stats[CC + tid], colsq[tid]);
    }
#undef STAGE_A
#undef STAGE_B
}

__global__ void finalize3_k(const float* __restrict__ stats,
                            const float* __restrict__ g1, const float* __restrict__ b1,
                            const float* __restrict__ g2, const float* __restrict__ b2,
                            const float* __restrict__ g3, const float* __restrict__ b3,
                            float* __restrict__ ss) {
    int a = blockIdx.x;
    int c = threadIdx.x;
    const float* g = (a == 0) ? g1 : (a == 1) ? g2 : g3;
    const float* b = (a == 0) ? b1 : (a == 1) ? b2 : b3;
    const float* st = stats + a * 2 * CC;
    float* s = ss + a * 2 * CC;
    float mu  = st[c] * (1.f / NP);
    float var = st[CC + c] * (1.f / NP) - mu * mu;
    float sc  = g[c] * rsqrtf(var + 1e-5f);
    s[c]      = sc;
    s[CC + c] = b[c] - mu * sc;
}

// out = (sigmoid(a1*h1+c1) + sigmoid(a2*h2+c2) + sigmoid(a3*h3+c3)) * feat(bf16)
__global__ void apply3_k(const unsigned short* __restrict__ h1,
                         const unsigned short* __restrict__ h2,
                         const unsigned short* __restrict__ h3,
                         const float* __restrict__ ss,
                         const unsigned short* __restrict__ fb, float* __restrict__ out) {
    size_t e = ((size_t)blockIdx.x * 256 + threadIdx.x) * 8;
    int c0 = (int)(e & (CC - 1));
    bf16x8 v1 = __builtin_nontemporal_load((const bf16x8*)(h1 + e));
    bf16x8 v2 = __builtin_nontemporal_load((const bf16x8*)(h2 + e));
    bf16x8 v3 = __builtin_nontemporal_load((const bf16x8*)(h3 + e));
    bf16x8 fv = *(const bf16x8*)(fb + e);
    float s[8];
    #pragma unroll
    for (int j = 0; j < 8; ++j) {
        float z1 = ss[c0 + j]          * bf2f((unsigned short)v1[j]) + ss[CC + c0 + j];
        float z2 = ss[2 * CC + c0 + j] * bf2f((unsigned short)v2[j]) + ss[3 * CC + c0 + j];
        float z3 = ss[4 * CC + c0 + j] * bf2f((unsigned short)v3[j]) + ss[5 * CC + c0 + j];
        float sg = 1.f / (1.f + __expf(-z1)) + 1.f / (1.f + __expf(-z2)) + 1.f / (1.f + __expf(-z3));
        s[j] = sg * bf2f((unsigned short)fv[j]);
    }
    f32x4* o = (f32x4*)(out + e);
    f32x4 o0 = {s[0], s[1], s[2], s[3]};
    f32x4 o1 = {s[4], s[5], s[6], s[7]};
    __builtin_nontemporal_store(o0, o);
    __builtin_nontemporal_store(o1, o + 1);
}

extern "C" void kernel_launch(void* const* d_in, const int* in_sizes, int n_in,
                              void* d_out, int out_size, void* d_ws, size_t ws_size,
                              hipStream_t stream) {
    const float* feat = (const float*)d_in[0];
    const float* W1   = (const float*)d_in[1];
    const float* W2   = (const float*)d_in[2];
    const float* W3   = (const float*)d_in[3];
    const float* g1   = (const float*)d_in[4];
    const float* b1   = (const float*)d_in[5];
    const float* g2   = (const float*)d_in[6];
    const float* b2   = (const float*)d_in[7];
    const float* g3   = (const float*)d_in[8];
    const float* b3   = (const float*)d_in[9];
    const int* nbr1   = (const int*)d_in[10];
    const int* nbr2   = (const int*)d_in[11];
    const int* nbr3   = (const int*)d_in[12];
    float* out = (float*)d_out;

    char* w = (char*)d_ws;
    unsigned short* fb   = (unsigned short*)w;  w += (size_t)(NP + 1) * CC * 2;
    unsigned short* wbT  = (unsigned short*)w;  w += (size_t)9 * CC * CC * 2;
    float* stats         = (float*)w;           w += (size_t)3 * 2 * CC * 4;
    float* ss            = (float*)w;           w += (size_t)3 * 2 * CC * 4;
    unsigned short* hbuf = (unsigned short*)w;  // 3 * N * C bf16

    zero_stats_k<<<6, 256, 0, stream>>>(stats);
    {
        size_t tot = (size_t)(NP + 1) * CC / 8;
        int blocks = (int)((tot + 255) / 256);
        cast_features_k<<<blocks, 256, 0, stream>>>(feat, fb);
    }
    cast_weights_k<<<2304, 256, 0, stream>>>(W1, W2, W3, wbT);

    gemm_conv_fused_k<<<dim3(512, 3), 512, 0, stream>>>(fb, wbT, nbr1, nbr2, nbr3,
                                                        hbuf, stats);
    finalize3_k<<<3, 256, 0, stream>>>(stats, g1, b1, g2, b2, g3, b3, ss);
    apply3_k<<<16384, 256, 0, stream>>>(hbuf,
                                        hbuf + (size_t)NP * CC,
                                        hbuf + (size_t)2 * NP * CC,
                                        ss, fb, out);
}

// Round 5
// 302.610 us; speedup vs baseline: 1.3404x; 1.3404x over previous
//
#include <hip/hip_runtime.h>
#include <hip/hip_bf16.h>

// RPL_Asymm_3d_spconv: 3x (3-tap gathered GEMM -> BN(train) -> sigmoid), then (s1+s2+s3)*features
// N=131072, C=256. bf16 MFMA path.
//
// Round 5 = Round 4 with the two diagnosed fixes:
//  - h epilogue stores PLAIN (not nontemporal): NT 2B stores caused partial-line
//    HBM write amplification (WRITE_SIZE 203->473MB, +135us)
//  - all 8 next-tile stages front-loaded into ph0 (4A+1B) / ph1 (3B): gathered-A
//    LLC-hit latency (~450cyc) now covered by ~64 MFMA + 3 barriers before the
//    per-tile vmcnt(0) drain
//  - bijective XCD swizzle on the 512 row-blocks (fb-gather L2 locality)

#define NP 131072
#define CC 256
#define BM 256
#define BK 64
#define ATILE (BM * BK)   // 16384 elems (32 KiB)
#define BTILE (256 * BK)

typedef __attribute__((ext_vector_type(4))) float f32x4;
typedef __attribute__((ext_vector_type(8))) short bf16x8;

__device__ __forceinline__ unsigned short f2bf(float f) {
    unsigned int u = __float_as_uint(f);
    u += 0x7FFFu + ((u >> 16) & 1u);   // RNE
    return (unsigned short)(u >> 16);
}
__device__ __forceinline__ float bf2f(unsigned short s) {
    return __uint_as_float(((unsigned int)s) << 16);
}

__device__ __forceinline__ void gload_lds16(const void* g, void* l) {
    __builtin_amdgcn_global_load_lds(
        (const __attribute__((address_space(1))) unsigned int*)g,
        (__attribute__((address_space(3))) unsigned int*)l, 16, 0, 0);
}

__global__ void zero_stats_k(float* stats) {
    int i = blockIdx.x * 256 + threadIdx.x;
    if (i < 3 * 2 * CC) stats[i] = 0.f;
}

__global__ void cast_features_k(const float* __restrict__ f, unsigned short* __restrict__ fb) {
    size_t e = ((size_t)blockIdx.x * 256 + threadIdx.x) * 8;
    const size_t tot = (size_t)(NP + 1) * CC;
    if (e >= tot) return;
    unsigned short tmp[8];
    if (e >= (size_t)NP * CC) {
        #pragma unroll
        for (int j = 0; j < 8; ++j) tmp[j] = 0;  // pad row
    } else {
        float4 v0 = *(const float4*)(f + e);
        float4 v1 = *(const float4*)(f + e + 4);
        tmp[0] = f2bf(v0.x); tmp[1] = f2bf(v0.y); tmp[2] = f2bf(v0.z); tmp[3] = f2bf(v0.w);
        tmp[4] = f2bf(v1.x); tmp[5] = f2bf(v1.y); tmp[6] = f2bf(v1.z); tmp[7] = f2bf(v1.w);
    }
    *(bf16x8*)(fb + e) = *(bf16x8*)tmp;
}

// wbT[m][cout][cin] = W_m[tap][cin][cout], m = axis*3+tap
__global__ void cast_weights_k(const float* __restrict__ W1, const float* __restrict__ W2,
                               const float* __restrict__ W3, unsigned short* __restrict__ wbT) {
    int bid  = blockIdx.x;        // 0..2303
    int m    = bid >> 8;          // 0..8
    int cout = bid & 255;
    int cin  = threadIdx.x;
    const float* W = (m < 3) ? W1 : (m < 6) ? W2 : W3;
    int tap = m - (m / 3) * 3;
    float v = W[((size_t)tap * CC + cin) * CC + cout];
    wbT[((size_t)m * CC + cout) * CC + cin] = f2bf(v);
}

#define MFMA16(a, b, c) __builtin_amdgcn_mfma_f32_16x16x32_bf16((a), (b), (c), 0, 0, 0)
#define LDF(base, row, swz) (*(const bf16x8*)((base) + (row) * BK + (swz)))

__global__ __launch_bounds__(512, 2)
void gemm_conv_fused_k(const unsigned short* __restrict__ fb,
                       const unsigned short* __restrict__ wbT,
                       const int* __restrict__ nbr1, const int* __restrict__ nbr2,
                       const int* __restrict__ nbr3,
                       unsigned short* __restrict__ hbase,
                       float* __restrict__ statsBase) {
    __shared__ unsigned short As[2 * ATILE];   // 64 KiB
    __shared__ unsigned short Bs[2 * BTILE];   // 64 KiB
    __shared__ float colsum[256];
    __shared__ float colsq[256];

    const int axis = blockIdx.y;
    const int* nbr = (axis == 0) ? nbr1 : (axis == 1) ? nbr2 : nbr3;
    const unsigned short* wA = wbT + (size_t)axis * 3 * CC * CC;
    unsigned short* h = hbase + (size_t)axis * NP * CC;
    float* stats = statsBase + axis * 2 * CC;

    const int tid     = threadIdx.x;
    const int lane    = tid & 63;
    const int wave    = tid >> 6;
    // bijective XCD swizzle (512 blocks, 512%8==0): 64 consecutive row-blocks per XCD
    const int bswz    = (blockIdx.x & 7) * 64 + (blockIdx.x >> 3);
    const int rowBase = bswz * BM;

    if (tid < 256) { colsum[tid] = 0.f; colsq[tid] = 0.f; }

    // per-thread staging constants: 4 loads each for A and B per K-tile
    int rstage[4], srcOff[4];
    int gA0[4], gA1[4], gA2[4];
    #pragma unroll
    for (int u = 0; u < 4; ++u) {
        int idx = u * 512 + tid;          // 16B-granule index within 256x64 tile
        int r = idx >> 3, p = idx & 7;
        rstage[u] = r;
        srcOff[u] = (p ^ (r & 7)) * 8;    // source element offset (inverse swizzle)
        int gi = rowBase + r;
        gA0[u] = nbr[(size_t)gi * 3 + 0];
        gA1[u] = nbr[(size_t)gi * 3 + 1];
        gA2[u] = nbr[(size_t)gi * 3 + 2];
    }

#define STAGE_A(u, Abuf, tapsel, kkE) do {                                    \
        int gr_ = ((tapsel) == 0) ? gA0[u] : ((tapsel) == 1) ? gA1[u] : gA2[u]; \
        gload_lds16(fb + (size_t)gr_ * CC + (kkE) + srcOff[u],                \
                    (Abuf) + ((u) * 512 + wave * 64) * 8);                    \
    } while (0)
#define STAGE_B(u, Bbuf, wTt, kkE)                                            \
        gload_lds16((wTt) + (size_t)rstage[u] * CC + (kkE) + srcOff[u],       \
                    (Bbuf) + ((u) * 512 + wave * 64) * 8)

    const int wr = wave >> 2;             // 0..1
    const int wc = wave & 3;              // 0..3
    const int fr = lane & 15;
    const int kq = lane >> 4;
    const int swz0 = (kq ^ (fr & 7)) * 8;        // ks=0 chunk (logical 0..3)
    const int swz1 = ((4 + kq) ^ (fr & 7)) * 8;  // ks=1 chunk (logical 4..7)
    const int rA = wr * 128 + fr;
    const int rB = wc * 64 + fr;

    f32x4 acc[8][4] = {};

    // prologue: stage K-tile 0 (tap 0, kk 0) then full drain
    STAGE_A(0, As, 0, 0); STAGE_A(1, As, 0, 0); STAGE_A(2, As, 0, 0); STAGE_A(3, As, 0, 0);
    STAGE_B(0, Bs, wA, 0); STAGE_B(1, Bs, wA, 0); STAGE_B(2, Bs, wA, 0); STAGE_B(3, Bs, wA, 0);
    __syncthreads();   // vmcnt(0)+lgkmcnt(0)+barrier once; also covers colsum init

    for (int t = 0; t < 12; ++t) {
        unsigned short* Ac = As + (t & 1) * ATILE;
        unsigned short* Bc = Bs + (t & 1) * BTILE;
        unsigned short* An = As + ((t & 1) ^ 1) * ATILE;
        unsigned short* Bn = Bs + ((t & 1) ^ 1) * BTILE;
        const int t1 = t + 1;
        const int tap1 = t1 >> 2;
        const int kk1 = (t1 & 3) * BK;
        const unsigned short* wT1 = wA + (size_t)tap1 * CC * CC;
        const bool st = (t < 11);

        bf16x8 aF[4][2], bLo[2][2], bHi[2][2];

        // ---------- phase 0: aF(m0..3) + bLo(n0..1); stage A0-A3,B0 (t+1) early
        #pragma unroll
        for (int m = 0; m < 4; ++m) {
            aF[m][0] = LDF(Ac, rA + m * 16, swz0);
            aF[m][1] = LDF(Ac, rA + m * 16, swz1);
        }
        #pragma unroll
        for (int n = 0; n < 2; ++n) {
            bLo[n][0] = LDF(Bc, rB + n * 16, swz0);
            bLo[n][1] = LDF(Bc, rB + n * 16, swz1);
        }
        if (st) {
            STAGE_A(0, An, tap1, kk1); STAGE_A(1, An, tap1, kk1);
            STAGE_A(2, An, tap1, kk1); STAGE_A(3, An, tap1, kk1);
            STAGE_B(0, Bn, wT1, kk1);
        }
        __builtin_amdgcn_s_barrier();
        __builtin_amdgcn_s_setprio(1);
        #pragma unroll
        for (int m = 0; m < 4; ++m)
            #pragma unroll
            for (int n = 0; n < 2; ++n) {
                acc[m][n] = MFMA16(aF[m][0], bLo[n][0], acc[m][n]);
                acc[m][n] = MFMA16(aF[m][1], bLo[n][1], acc[m][n]);
            }
        __builtin_amdgcn_s_setprio(0);
        __builtin_amdgcn_s_barrier();

        // ---------- phase 1: bHi(n2..3); stage B1-B3 (t+1)
        #pragma unroll
        for (int n = 0; n < 2; ++n) {
            bHi[n][0] = LDF(Bc, rB + (n + 2) * 16, swz0);
            bHi[n][1] = LDF(Bc, rB + (n + 2) * 16, swz1);
        }
        if (st) { STAGE_B(1, Bn, wT1, kk1); STAGE_B(2, Bn, wT1, kk1); STAGE_B(3, Bn, wT1, kk1); }
        __builtin_amdgcn_s_barrier();
        __builtin_amdgcn_s_setprio(1);
        #pragma unroll
        for (int m = 0; m < 4; ++m)
            #pragma unroll
            for (int n = 0; n < 2; ++n) {
                acc[m][n + 2] = MFMA16(aF[m][0], bHi[n][0], acc[m][n + 2]);
                acc[m][n + 2] = MFMA16(aF[m][1], bHi[n][1], acc[m][n + 2]);
            }
        __builtin_amdgcn_s_setprio(0);
        __builtin_amdgcn_s_barrier();

        // ---------- phase 2: aF(m4..7) overwrite; no stages
        #pragma unroll
        for (int m = 0; m < 4; ++m) {
            aF[m][0] = LDF(Ac, rA + (m + 4) * 16, swz0);
            aF[m][1] = LDF(Ac, rA + (m + 4) * 16, swz1);
        }
        __builtin_amdgcn_s_barrier();
        __builtin_amdgcn_s_setprio(1);
        #pragma unroll
        for (int m = 0; m < 4; ++m)
            #pragma unroll
            for (int n = 0; n < 2; ++n) {
                acc[m + 4][n + 2] = MFMA16(aF[m][0], bHi[n][0], acc[m + 4][n + 2]);
                acc[m + 4][n + 2] = MFMA16(aF[m][1], bHi[n][1], acc[m + 4][n + 2]);
            }
        __builtin_amdgcn_s_setprio(0);
        __builtin_amdgcn_s_barrier();

        // ---------- phase 3: MFMA (m4..7 x n0..1); boundary drain
        __builtin_amdgcn_s_setprio(1);
        #pragma unroll
        for (int m = 0; m < 4; ++m)
            #pragma unroll
            for (int n = 0; n < 2; ++n) {
                acc[m + 4][n] = MFMA16(aF[m][0], bLo[n][0], acc[m + 4][n]);
                acc[m + 4][n] = MFMA16(aF[m][1], bLo[n][1], acc[m + 4][n]);
            }
        __builtin_amdgcn_s_setprio(0);
        if (st) asm volatile("s_waitcnt vmcnt(0)" ::: "memory");
        __builtin_amdgcn_s_barrier();
    }

    // epilogue: C/D layout col=lane&15, row=(lane>>4)*4+reg; h store + fused stats
    // PLAIN stores (L2 write-combining) — NT 2B stores amplified HBM writes 2.3x
    const int orow = (lane >> 4) * 4;
    float psum[4], psq[4];
    #pragma unroll
    for (int n = 0; n < 4; ++n) { psum[n] = 0.f; psq[n] = 0.f; }
    #pragma unroll
    for (int m = 0; m < 8; ++m) {
        #pragma unroll
        for (int n = 0; n < 4; ++n) {
            int col = wc * 64 + n * 16 + fr;
            int row = rowBase + wr * 128 + m * 16 + orow;
            #pragma unroll
            for (int j = 0; j < 4; ++j) {
                unsigned short hb = f2bf(acc[m][n][j]);
                float v = bf2f(hb);
                h[(size_t)(row + j) * CC + col] = hb;
                psum[n] += v;
                psq[n]  += v * v;
            }
        }
    }
    #pragma unroll
    for (int n = 0; n < 4; ++n) {
        psum[n] += __shfl_xor(psum[n], 16);
        psum[n] += __shfl_xor(psum[n], 32);
        psq[n]  += __shfl_xor(psq[n], 16);
        psq[n]  += __shfl_xor(psq[n], 32);
    }
    if ((lane >> 4) == 0) {
        #pragma unroll
        for (int n = 0; n < 4; ++n) {
            int cl = wc * 64 + n * 16 + fr;
            atomicAdd(&colsum[cl], psum[n]);
            atomicAdd(&colsq[cl],  psq[n]);
        }
    }
    __syncthreads();
    if (tid < 256) {
        atomicAdd(&stats[tid],      colsum[tid]);
        atomicAdd(&stats[CC + tid], colsq[tid]);
    }
#undef STAGE_A
#undef STAGE_B
}

__global__ void finalize3_k(const float* __restrict__ stats,
                            const float* __restrict__ g1, const float* __restrict__ b1,
                            const float* __restrict__ g2, const float* __restrict__ b2,
                            const float* __restrict__ g3, const float* __restrict__ b3,
                            float* __restrict__ ss) {
    int a = blockIdx.x;
    int c = threadIdx.x;
    const float* g = (a == 0) ? g1 : (a == 1) ? g2 : g3;
    const float* b = (a == 0) ? b1 : (a == 1) ? b2 : b3;
    const float* st = stats + a * 2 * CC;
    float* s = ss + a * 2 * CC;
    float mu  = st[c] * (1.f / NP);
    float var = st[CC + c] * (1.f / NP) - mu * mu;
    float sc  = g[c] * rsqrtf(var + 1e-5f);
    s[c]      = sc;
    s[CC + c] = b[c] - mu * sc;
}

// out = (sigmoid(a1*h1+c1) + sigmoid(a2*h2+c2) + sigmoid(a3*h3+c3)) * feat(bf16)
__global__ void apply3_k(const unsigned short* __restrict__ h1,
                         const unsigned short* __restrict__ h2,
                         const unsigned short* __restrict__ h3,
                         const float* __restrict__ ss,
                         const unsigned short* __restrict__ fb, float* __restrict__ out) {
    size_t e = ((size_t)blockIdx.x * 256 + threadIdx.x) * 8;
    int c0 = (int)(e & (CC - 1));
    bf16x8 v1 = __builtin_nontemporal_load((const bf16x8*)(h1 + e));
    bf16x8 v2 = __builtin_nontemporal_load((const bf16x8*)(h2 + e));
    bf16x8 v3 = __builtin_nontemporal_load((const bf16x8*)(h3 + e));
    bf16x8 fv = *(const bf16x8*)(fb + e);
    float s[8];
    #pragma unroll
    for (int j = 0; j < 8; ++j) {
        float z1 = ss[c0 + j]          * bf2f((unsigned short)v1[j]) + ss[CC + c0 + j];
        float z2 = ss[2 * CC + c0 + j] * bf2f((unsigned short)v2[j]) + ss[3 * CC + c0 + j];
        float z3 = ss[4 * CC + c0 + j] * bf2f((unsigned short)v3[j]) + ss[5 * CC + c0 + j];
        float sg = 1.f / (1.f + __expf(-z1)) + 1.f / (1.f + __expf(-z2)) + 1.f / (1.f + __expf(-z3));
        s[j] = sg * bf2f((unsigned short)fv[j]);
    }
    f32x4* o = (f32x4*)(out + e);
    f32x4 o0 = {s[0], s[1], s[2], s[3]};
    f32x4 o1 = {s[4], s[5], s[6], s[7]};
    __builtin_nontemporal_store(o0, o);
    __builtin_nontemporal_store(o1, o + 1);
}

extern "C" void kernel_launch(void* const* d_in, const int* in_sizes, int n_in,
                              void* d_out, int out_size, void* d_ws, size_t ws_size,
                              hipStream_t stream) {
    const float* feat = (const float*)d_in[0];
    const float* W1   = (const float*)d_in[1];
    const float* W2   = (const float*)d_in[2];
    const float* W3   = (const float*)d_in[3];
    const float* g1   = (const float*)d_in[4];
    const float* b1   = (const float*)d_in[5];
    const float* g2   = (const float*)d_in[6];
    const float* b2   = (const float*)d_in[7];
    const float* g3   = (const float*)d_in[8];
    const float* b3   = (const float*)d_in[9];
    const int* nbr1   = (const int*)d_in[10];
    const int* nbr2   = (const int*)d_in[11];
    const int* nbr3   = (const int*)d_in[12];
    float* out = (float*)d_out;

    char* w = (char*)d_ws;
    unsigned short* fb   = (unsigned short*)w;  w += (size_t)(NP + 1) * CC * 2;
    unsigned short* wbT  = (unsigned short*)w;  w += (size_t)9 * CC * CC * 2;
    float* stats         = (float*)w;           w += (size_t)3 * 2 * CC * 4;
    float* ss            = (float*)w;           w += (size_t)3 * 2 * CC * 4;
    unsigned short* hbuf = (unsigned short*)w;  // 3 * N * C bf16

    zero_stats_k<<<6, 256, 0, stream>>>(stats);
    {
        size_t tot = (size_t)(NP + 1) * CC / 8;
        int blocks = (int)((tot + 255) / 256);
        cast_features_k<<<blocks, 256, 0, stream>>>(feat, fb);
    }
    cast_weights_k<<<2304, 256, 0, stream>>>(W1, W2, W3, wbT);

    gemm_conv_fused_k<<<dim3(512, 3), 512, 0, stream>>>(fb, wbT, nbr1, nbr2, nbr3,
                                                        hbuf, stats);
    finalize3_k<<<3, 256, 0, stream>>>(stats, g1, b1, g2, b2, g3, b3, ss);
    apply3_k<<<16384, 256, 0, stream>>>(hbuf,
                                        hbuf + (size_t)NP * CC,
                                        hbuf + (size_t)2 * NP * CC,
                                        ss, fb, out);
}

// Round 6
// 276.488 us; speedup vs baseline: 1.4670x; 1.0945x over previous
//
#include <hip/hip_runtime.h>
#include <hip/hip_bf16.h>

// RPL_Asymm_3d_spconv: 3x (3-tap gathered GEMM -> BN(train) -> sigmoid), then (s1+s2+s3)*features
// N=131072, C=256. bf16 MFMA path.
//
// Round 6: occupancy-first gathered GEMM.
//  - per-wave 64x64 (acc[4][4]=64 AGPR, ~130 regs -> 3 waves/SIMD), 4-wave blocks,
//    tile 128x128, BK=32, LDS dbuf 32KiB -> 3 blocks/CU (12 waves, was 8)
//  - minimal 2-phase: STAGE(t+1) -> ds_read/MFMA(t) -> one __syncthreads per step
//  - chunk-XOR swizzle p = g ^ ((r>>1)&3): quarter-wave aliasing 2-way (free, m136)
//  - fused BN stats epilogue, XCD-swizzled blocks, single fused apply pass

#define NP 131072
#define CC 256
#define TILEE (128 * 32)   // elems per LDS tile buffer

typedef __attribute__((ext_vector_type(4))) float f32x4;
typedef __attribute__((ext_vector_type(8))) short bf16x8;

__device__ __forceinline__ unsigned short f2bf(float f) {
    unsigned int u = __float_as_uint(f);
    u += 0x7FFFu + ((u >> 16) & 1u);   // RNE
    return (unsigned short)(u >> 16);
}
__device__ __forceinline__ float bf2f(unsigned short s) {
    return __uint_as_float(((unsigned int)s) << 16);
}

__device__ __forceinline__ void gload_lds16(const void* g, void* l) {
    __builtin_amdgcn_global_load_lds(
        (const __attribute__((address_space(1))) unsigned int*)g,
        (__attribute__((address_space(3))) unsigned int*)l, 16, 0, 0);
}

__global__ void zero_stats_k(float* stats) {
    int i = blockIdx.x * 256 + threadIdx.x;
    if (i < 3 * 2 * CC) stats[i] = 0.f;
}

__global__ void cast_features_k(const float* __restrict__ f, unsigned short* __restrict__ fb) {
    size_t e = ((size_t)blockIdx.x * 256 + threadIdx.x) * 8;
    const size_t tot = (size_t)(NP + 1) * CC;
    if (e >= tot) return;
    unsigned short tmp[8];
    if (e >= (size_t)NP * CC) {
        #pragma unroll
        for (int j = 0; j < 8; ++j) tmp[j] = 0;  // pad row
    } else {
        float4 v0 = *(const float4*)(f + e);
        float4 v1 = *(const float4*)(f + e + 4);
        tmp[0] = f2bf(v0.x); tmp[1] = f2bf(v0.y); tmp[2] = f2bf(v0.z); tmp[3] = f2bf(v0.w);
        tmp[4] = f2bf(v1.x); tmp[5] = f2bf(v1.y); tmp[6] = f2bf(v1.z); tmp[7] = f2bf(v1.w);
    }
    *(bf16x8*)(fb + e) = *(bf16x8*)tmp;
}

// wbT[m][cout][cin] = W_m[tap][cin][cout], m = axis*3+tap
__global__ void cast_weights_k(const float* __restrict__ W1, const float* __restrict__ W2,
                               const float* __restrict__ W3, unsigned short* __restrict__ wbT) {
    int bid  = blockIdx.x;        // 0..2303
    int m    = bid >> 8;          // 0..8
    int cout = bid & 255;
    int cin  = threadIdx.x;
    const float* W = (m < 3) ? W1 : (m < 6) ? W2 : W3;
    int tap = m - (m / 3) * 3;
    float v = W[((size_t)tap * CC + cin) * CC + cout];
    wbT[((size_t)m * CC + cout) * CC + cin] = f2bf(v);
}

#define MFMA16(a, b, c) __builtin_amdgcn_mfma_f32_16x16x32_bf16((a), (b), (c), 0, 0, 0)

__global__ __launch_bounds__(256, 3)
void gemm_conv_fused_k(const unsigned short* __restrict__ fb,
                       const unsigned short* __restrict__ wbT,
                       const int* __restrict__ nbr1, const int* __restrict__ nbr2,
                       const int* __restrict__ nbr3,
                       unsigned short* __restrict__ hbase,
                       float* __restrict__ statsBase) {
    __shared__ unsigned short As[2][TILEE];   // 2 x 8 KiB
    __shared__ unsigned short Bs[2][TILEE];   // 2 x 8 KiB
    __shared__ float colsum[128];
    __shared__ float colsq[128];

    const int axis = blockIdx.y;
    const int* nbr = (axis == 0) ? nbr1 : (axis == 1) ? nbr2 : nbr3;
    const unsigned short* wA = wbT + (size_t)axis * 3 * CC * CC;
    unsigned short* h = hbase + (size_t)axis * NP * CC;
    float* stats = statsBase + axis * 2 * CC;

    const int tid  = threadIdx.x;
    const int lane = tid & 63;
    const int wave = tid >> 6;
    // bijective XCD swizzle over 2048 blocks (2048 % 8 == 0)
    const int bx   = blockIdx.x;
    const int swzb = (bx & 7) * 256 + (bx >> 3);
    const int rowBase = (swzb >> 1) * 128;
    const int colBase = (swzb & 1) * 128;

    if (tid < 128) { colsum[tid] = 0.f; colsq[tid] = 0.f; }

    // staging constants: 2 A-granules + 2 B-granules per thread per K-step
    int srcOff[2], gA0[2], gA1[2], gA2[2], bRow[2];
    #pragma unroll
    for (int u = 0; u < 2; ++u) {
        int idx = u * 256 + tid;          // 16B-granule index in 128x32 tile
        int r = idx >> 2, p = idx & 3;
        srcOff[u] = (p ^ ((r >> 1) & 3)) * 8;   // inverse swizzle on source
        int gi = rowBase + r;
        gA0[u] = nbr[(size_t)gi * 3 + 0];
        gA1[u] = nbr[(size_t)gi * 3 + 1];
        gA2[u] = nbr[(size_t)gi * 3 + 2];
        bRow[u] = colBase + r;
    }

#define STAGE_A(u, Abuf, tapsel, kkE) do {                                      \
        int gr_ = ((tapsel) == 0) ? gA0[u] : ((tapsel) == 1) ? gA1[u] : gA2[u]; \
        gload_lds16(fb + (size_t)gr_ * CC + (kkE) + srcOff[u],                  \
                    (Abuf) + ((u) * 256 + tid) * 8);                            \
    } while (0)
#define STAGE_B(u, Bbuf, wTt, kkE)                                              \
        gload_lds16((wTt) + (size_t)bRow[u] * CC + (kkE) + srcOff[u],           \
                    (Bbuf) + ((u) * 256 + tid) * 8)

    const int wr = (wave >> 1) & 1;
    const int wc = wave & 1;
    const int fr = lane & 15;
    const int kq = lane >> 4;
    const int chunkOff = (kq ^ ((fr >> 1) & 3)) * 8;  // read-side swizzle (elems)
    const int rA = wr * 64 + fr;
    const int rB = wc * 64 + fr;

    f32x4 acc[4][4] = {};

    // prologue: stage K-step 0 (tap 0, kk 0)
    STAGE_A(0, As[0], 0, 0); STAGE_A(1, As[0], 0, 0);
    STAGE_B(0, Bs[0], wA, 0); STAGE_B(1, Bs[0], wA, 0);
    __syncthreads();

    for (int t = 0; t < 24; ++t) {
        const unsigned short* Ac = As[t & 1];
        const unsigned short* Bc = Bs[t & 1];
        unsigned short* An = As[(t + 1) & 1];
        unsigned short* Bn = Bs[(t + 1) & 1];
        const int t1 = t + 1;
        const int tap1 = t1 >> 3;
        const int kk1 = (t1 & 7) * 32;

        if (t < 23) {
            const unsigned short* wT1 = wA + (size_t)tap1 * CC * CC;
            STAGE_A(0, An, tap1, kk1); STAGE_A(1, An, tap1, kk1);
            STAGE_B(0, Bn, wT1, kk1);  STAGE_B(1, Bn, wT1, kk1);
        }

        bf16x8 aF[4], bF[4];
        #pragma unroll
        for (int m = 0; m < 4; ++m)
            aF[m] = *(const bf16x8*)(Ac + (rA + m * 16) * 32 + chunkOff);
        #pragma unroll
        for (int n = 0; n < 4; ++n)
            bF[n] = *(const bf16x8*)(Bc + (rB + n * 16) * 32 + chunkOff);
        #pragma unroll
        for (int m = 0; m < 4; ++m)
            #pragma unroll
            for (int n = 0; n < 4; ++n)
                acc[m][n] = MFMA16(aF[m], bF[n], acc[m][n]);

        __syncthreads();
    }

    // epilogue: C/D layout col=lane&15, row=(lane>>4)*4+reg; h store + fused stats
    const int orow = (lane >> 4) * 4;
    float psum[4], psq[4];
    #pragma unroll
    for (int n = 0; n < 4; ++n) { psum[n] = 0.f; psq[n] = 0.f; }
    #pragma unroll
    for (int m = 0; m < 4; ++m) {
        #pragma unroll
        for (int n = 0; n < 4; ++n) {
            int col = colBase + wc * 64 + n * 16 + fr;
            int row = rowBase + wr * 64 + m * 16 + orow;
            #pragma unroll
            for (int j = 0; j < 4; ++j) {
                unsigned short hb = f2bf(acc[m][n][j]);
                float v = bf2f(hb);
                h[(size_t)(row + j) * CC + col] = hb;
                psum[n] += v;
                psq[n]  += v * v;
            }
        }
    }
    #pragma unroll
    for (int n = 0; n < 4; ++n) {
        psum[n] += __shfl_xor(psum[n], 16);
        psum[n] += __shfl_xor(psum[n], 32);
        psq[n]  += __shfl_xor(psq[n], 16);
        psq[n]  += __shfl_xor(psq[n], 32);
    }
    if ((lane >> 4) == 0) {
        #pragma unroll
        for (int n = 0; n < 4; ++n) {
            int cl = wc * 64 + n * 16 + fr;   // local col 0..127
            atomicAdd(&colsum[cl], psum[n]);
            atomicAdd(&colsq[cl],  psq[n]);
        }
    }
    __syncthreads();
    if (tid < 128) {
        int c = colBase + tid;
        atomicAdd(&stats[c],      colsum[tid]);
        atomicAdd(&stats[CC + c], colsq[tid]);
    }
#undef STAGE_A
#undef STAGE_B
}

__global__ void finalize3_k(const float* __restrict__ stats,
                            const float* __restrict__ g1, const float* __restrict__ b1,
                            const float* __restrict__ g2, const float* __restrict__ b2,
                            const float* __restrict__ g3, const float* __restrict__ b3,
                            float* __restrict__ ss) {
    int a = blockIdx.x;
    int c = threadIdx.x;
    const float* g = (a == 0) ? g1 : (a == 1) ? g2 : g3;
    const float* b = (a == 0) ? b1 : (a == 1) ? b2 : b3;
    const float* st = stats + a * 2 * CC;
    float* s = ss + a * 2 * CC;
    float mu  = st[c] * (1.f / NP);
    float var = st[CC + c] * (1.f / NP) - mu * mu;
    float sc  = g[c] * rsqrtf(var + 1e-5f);
    s[c]      = sc;
    s[CC + c] = b[c] - mu * sc;
}

// out = (sigmoid(a1*h1+c1) + sigmoid(a2*h2+c2) + sigmoid(a3*h3+c3)) * feat(bf16)
__global__ void apply3_k(const unsigned short* __restrict__ h1,
                         const unsigned short* __restrict__ h2,
                         const unsigned short* __restrict__ h3,
                         const float* __restrict__ ss,
                         const unsigned short* __restrict__ fb, float* __restrict__ out) {
    size_t e = ((size_t)blockIdx.x * 256 + threadIdx.x) * 8;
    int c0 = (int)(e & (CC - 1));
    bf16x8 v1 = __builtin_nontemporal_load((const bf16x8*)(h1 + e));
    bf16x8 v2 = __builtin_nontemporal_load((const bf16x8*)(h2 + e));
    bf16x8 v3 = __builtin_nontemporal_load((const bf16x8*)(h3 + e));
    bf16x8 fv = *(const bf16x8*)(fb + e);
    float s[8];
    #pragma unroll
    for (int j = 0; j < 8; ++j) {
        float z1 = ss[c0 + j]          * bf2f((unsigned short)v1[j]) + ss[CC + c0 + j];
        float z2 = ss[2 * CC + c0 + j] * bf2f((unsigned short)v2[j]) + ss[3 * CC + c0 + j];
        float z3 = ss[4 * CC + c0 + j] * bf2f((unsigned short)v3[j]) + ss[5 * CC + c0 + j];
        float sg = 1.f / (1.f + __expf(-z1)) + 1.f / (1.f + __expf(-z2)) + 1.f / (1.f + __expf(-z3));
        s[j] = sg * bf2f((unsigned short)fv[j]);
    }
    f32x4* o = (f32x4*)(out + e);
    f32x4 o0 = {s[0], s[1], s[2], s[3]};
    f32x4 o1 = {s[4], s[5], s[6], s[7]};
    __builtin_nontemporal_store(o0, o);
    __builtin_nontemporal_store(o1, o + 1);
}

extern "C" void kernel_launch(void* const* d_in, const int* in_sizes, int n_in,
                              void* d_out, int out_size, void* d_ws, size_t ws_size,
                              hipStream_t stream) {
    const float* feat = (const float*)d_in[0];
    const float* W1   = (const float*)d_in[1];
    const float* W2   = (const float*)d_in[2];
    const float* W3   = (const float*)d_in[3];
    const float* g1   = (const float*)d_in[4];
    const float* b1   = (const float*)d_in[5];
    const float* g2   = (const float*)d_in[6];
    const float* b2   = (const float*)d_in[7];
    const float* g3   = (const float*)d_in[8];
    const float* b3   = (const float*)d_in[9];
    const int* nbr1   = (const int*)d_in[10];
    const int* nbr2   = (const int*)d_in[11];
    const int* nbr3   = (const int*)d_in[12];
    float* out = (float*)d_out;

    char* w = (char*)d_ws;
    unsigned short* fb   = (unsigned short*)w;  w += (size_t)(NP + 1) * CC * 2;
    unsigned short* wbT  = (unsigned short*)w;  w += (size_t)9 * CC * CC * 2;
    float* stats         = (float*)w;           w += (size_t)3 * 2 * CC * 4;
    float* ss            = (float*)w;           w += (size_t)3 * 2 * CC * 4;
    unsigned short* hbuf = (unsigned short*)w;  // 3 * N * C bf16

    zero_stats_k<<<6, 256, 0, stream>>>(stats);
    {
        size_t tot = (size_t)(NP + 1) * CC / 8;
        int blocks = (int)((tot + 255) / 256);
        cast_features_k<<<blocks, 256, 0, stream>>>(feat, fb);
    }
    cast_weights_k<<<2304, 256, 0, stream>>>(W1, W2, W3, wbT);

    gemm_conv_fused_k<<<dim3(2048, 3), 256, 0, stream>>>(fb, wbT, nbr1, nbr2, nbr3,
                                                         hbuf, stats);
    finalize3_k<<<3, 256, 0, stream>>>(stats, g1, b1, g2, b2, g3, b3, ss);
    apply3_k<<<16384, 256, 0, stream>>>(hbuf,
                                        hbuf + (size_t)NP * CC,
                                        hbuf + (size_t)2 * NP * CC,
                                        ss, fb, out);
}